// Round 5
// baseline (509.400 us; speedup 1.0000x reference)
//
#include <hip/hip_runtime.h>

// EdgeGATConv: h = x@fc_w^T + fc_b;  alpha = leaky_relu(Wi@h[src] + Wj@h[dst] + We@ea + att_b)
// out[src] += h[dst] * alpha
// N=50000, C=128, H=64, E_DIM=16, E=800000

#define GLDS4(gp, lp)                                                          \
    __builtin_amdgcn_global_load_lds(                                          \
        (const __attribute__((address_space(1))) unsigned int*)(gp),           \
        (__attribute__((address_space(3))) unsigned int*)(lp), 4, 0, 0)
#define GLDS16(gp, lp)                                                         \
    __builtin_amdgcn_global_load_lds(                                          \
        (const __attribute__((address_space(1))) unsigned int*)(gp),           \
        (__attribute__((address_space(3))) unsigned int*)(lp), 16, 0, 0)

#define WAITVM_(n) asm volatile("s_waitcnt vmcnt(" #n ")" ::: "memory")
#define WAITVM(n)                                                              \
    do { WAITVM_(n); __builtin_amdgcn_sched_barrier(0); } while (0)

// Node kernel: batch-4 nodes per wave to amortize LDS weight-row reads
// (LDS-pipe bound: ~64 b128 weight reads/node at batch-1). 256 threads +
// launch_bounds(256,2): VGPR cap 256 -> no spill (R2/R3's 128-cap spilled).
__global__ __launch_bounds__(256, 2) void node_kernel(
    const float* __restrict__ x,
    const float* __restrict__ fc_w, const float* __restrict__ fc_b,
    const float* __restrict__ att_w, const float* __restrict__ att_b,
    float* __restrict__ ai_out, float* __restrict__ h_out,
    float* __restrict__ aj_out, int N)
{
    __shared__ __align__(16) float4 wF[64 * 32];  // fc_w rows [64][128]
    __shared__ __align__(16) float4 wI[64 * 16];  // att_w[:, 0:64]
    __shared__ __align__(16) float4 wJ[64 * 16];  // att_w[:, 64:128]
    __shared__ __align__(16) float xs[4][4][128]; // [wave][node][128]
    __shared__ __align__(16) float hs[4][4][64];

    const int t = threadIdx.x;
    for (int idx = t; idx < 64 * 32; idx += 256) {
        int l = idx >> 5, c = idx & 31;
        wF[l * 32 + (c ^ (l & 31))] =
            *reinterpret_cast<const float4*>(fc_w + l * 128 + c * 4);
    }
    for (int idx = t; idx < 64 * 16; idx += 256) {
        int l = idx >> 4, c = idx & 15;
        wI[l * 16 + (c ^ (l & 15))] =
            *reinterpret_cast<const float4*>(att_w + l * 144 + c * 4);
        wJ[l * 16 + (c ^ (l & 15))] =
            *reinterpret_cast<const float4*>(att_w + l * 144 + 64 + c * 4);
    }
    __syncthreads();

    const int w = t >> 6, l = t & 63;
    const float bF = fc_b[l];
    const float bA = att_b[l];   // fold att_b into a_i
    const int waveId = blockIdx.x * 4 + w;
    const int nWaves = gridDim.x * 4;
    const float2* x2 = reinterpret_cast<const float2*>(x);

    for (int n0 = waveId * 4; n0 < N; n0 += nWaves * 4) {
        const int nb = min(4, N - n0);
        #pragma unroll
        for (int m = 0; m < 4; ++m) {
            if (m < nb) {
                float2 xv = x2[(size_t)(n0 + m) * 64 + l];
                xs[w][m][2 * l] = xv.x;
                xs[w][m][2 * l + 1] = xv.y;
            }
        }
        float acc[4] = {bF, bF, bF, bF};
        #pragma unroll
        for (int c = 0; c < 32; ++c) {
            float4 wv = wF[l * 32 + (c ^ (l & 31))];
            #pragma unroll
            for (int m = 0; m < 4; ++m) {
                float4 xc = *reinterpret_cast<const float4*>(&xs[w][m][c * 4]);
                acc[m] = fmaf(wv.x, xc.x, acc[m]);
                acc[m] = fmaf(wv.y, xc.y, acc[m]);
                acc[m] = fmaf(wv.z, xc.z, acc[m]);
                acc[m] = fmaf(wv.w, xc.w, acc[m]);
            }
        }
        #pragma unroll
        for (int m = 0; m < 4; ++m) hs[w][m][l] = acc[m];
        float a2[4] = {bA, bA, bA, bA};
        float a3[4] = {0.f, 0.f, 0.f, 0.f};
        #pragma unroll
        for (int c = 0; c < 16; ++c) {
            float4 wi = wI[l * 16 + (c ^ (l & 15))];
            float4 wj = wJ[l * 16 + (c ^ (l & 15))];
            #pragma unroll
            for (int m = 0; m < 4; ++m) {
                float4 hv = *reinterpret_cast<const float4*>(&hs[w][m][c * 4]);
                a2[m] = fmaf(wi.x, hv.x, a2[m]); a2[m] = fmaf(wi.y, hv.y, a2[m]);
                a2[m] = fmaf(wi.z, hv.z, a2[m]); a2[m] = fmaf(wi.w, hv.w, a2[m]);
                a3[m] = fmaf(wj.x, hv.x, a3[m]); a3[m] = fmaf(wj.y, hv.y, a3[m]);
                a3[m] = fmaf(wj.z, hv.z, a3[m]); a3[m] = fmaf(wj.w, hv.w, a3[m]);
            }
        }
        #pragma unroll
        for (int m = 0; m < 4; ++m) {
            if (m < nb) {
                ai_out[(size_t)(n0 + m) * 64 + l] = a2[m];
                h_out[(size_t)(n0 + m) * 64 + l]  = acc[m];
                aj_out[(size_t)(n0 + m) * 64 + l] = a3[m];
            }
        }
    }
}

// Edge kernel: per wave one 64-edge tile. Gathers staged via async
// global_load_lds (wave-uniform base + lane*4 = exactly our access pattern),
// 8-edge chunks ping-ponged with COUNTED vmcnt waits (atomics + next chunk
// stay in flight; never drain to 0 in the loop).
__global__ __launch_bounds__(128) void edge_kernel(
    const int* __restrict__ ei,       // [2, E]
    const float* __restrict__ ea,     // [E, 16]
    const float* __restrict__ ai,     // [N, 64]  Wi@h + att_b
    const float* __restrict__ hv,     // [N, 64]  h
    const float* __restrict__ aj,     // [N, 64]  Wj@h
    const float* __restrict__ att_w,  // [64, 144]
    float* __restrict__ out, int E)
{
    // per-wave 16 KiB: ea_s[1024] | bufA[1536] | bufB[1536]
    // buf slot k: ai at +k*192, h at +k*192+64, aj at +k*192+128 (floats)
    __shared__ __align__(16) float lds[2][4096];

    const int t = threadIdx.x, w = t >> 6, l = t & 63;
    float* L = lds[w];
    float* ea_s = L;
    float* bufA = L + 1024;
    float* bufB = L + 2560;

    float we[16];
    #pragma unroll
    for (int k = 0; k < 16; ++k) we[k] = att_w[l * 144 + 128 + k];

    const int waveId = blockIdx.x * 2 + w;
    const int e0 = waveId * 64;
    if (e0 >= E) return;
    const int nE = min(64, E - e0);

    int src = 0, dst = 0;
    if (l < nE) { src = ei[e0 + l]; dst = ei[E + e0 + l]; }

#define ISSUE(c, buf)                                                          \
    {                                                                          \
        _Pragma("unroll") for (int k = 0; k < 8; ++k) {                        \
            int e_ = (c) * 8 + k;                                              \
            int s_ = __shfl(src, e_);                                          \
            int d_ = __shfl(dst, e_);                                          \
            GLDS4(ai + (size_t)s_ * 64 + l, (buf) + k * 192);                  \
            GLDS4(hv + (size_t)d_ * 64 + l, (buf) + k * 192 + 64);             \
            GLDS4(aj + (size_t)d_ * 64 + l, (buf) + k * 192 + 128);            \
        }                                                                      \
    }

#define FMA16(pre, v0, v1, v2, v3)                                             \
    pre = fmaf(we[0], (v0).x, pre);  pre = fmaf(we[1], (v0).y, pre);           \
    pre = fmaf(we[2], (v0).z, pre);  pre = fmaf(we[3], (v0).w, pre);           \
    pre = fmaf(we[4], (v1).x, pre);  pre = fmaf(we[5], (v1).y, pre);           \
    pre = fmaf(we[6], (v1).z, pre);  pre = fmaf(we[7], (v1).w, pre);           \
    pre = fmaf(we[8], (v2).x, pre);  pre = fmaf(we[9], (v2).y, pre);           \
    pre = fmaf(we[10], (v2).z, pre); pre = fmaf(we[11], (v2).w, pre);          \
    pre = fmaf(we[12], (v3).x, pre); pre = fmaf(we[13], (v3).y, pre);          \
    pre = fmaf(we[14], (v3).z, pre); pre = fmaf(we[15], (v3).w, pre)

#define COMPUTE(c, buf)                                                        \
    {                                                                          \
        _Pragma("unroll") for (int k = 0; k < 8; ++k) {                        \
            int e_ = (c) * 8 + k;                                              \
            int s_ = __shfl(src, e_);                                          \
            float av = (buf)[k * 192 + l];                                     \
            float hh = (buf)[k * 192 + 64 + l];                                \
            float a2 = (buf)[k * 192 + 128 + l];                               \
            const float4* eav = reinterpret_cast<const float4*>(ea_s + e_ * 16); \
            float4 v0 = eav[0], v1 = eav[1], v2 = eav[2], v3 = eav[3];         \
            float pre = av + a2;                                               \
            FMA16(pre, v0, v1, v2, v3);                                        \
            float alpha = pre > 0.f ? pre : 0.2f * pre;                        \
            atomicAdd(&out[(size_t)s_ * 64 + l], hh * alpha);                  \
        }                                                                      \
    }

    if (nE == 64) {
        // stage ea tile: 4 x (64 lanes x 16B) = 4 KiB, linear
        #pragma unroll
        for (int r = 0; r < 4; ++r)
            GLDS16(ea + (size_t)e0 * 16 + r * 256 + l * 4, ea_s + r * 256);

        ISSUE(0, bufA);
        ISSUE(1, bufB);
        WAITVM(24);          // ea + chunk0 done (chunk1's 24 still in flight)
        COMPUTE(0, bufA);
        ISSUE(2, bufA);
        WAITVM(32);          // chunk1 done (8 atomics + 24 loads in flight)
        COMPUTE(1, bufB);
        ISSUE(3, bufB);
        WAITVM(32);
        COMPUTE(2, bufA);
        ISSUE(4, bufA);
        WAITVM(32);
        COMPUTE(3, bufB);
        ISSUE(5, bufB);
        WAITVM(32);
        COMPUTE(4, bufA);
        ISSUE(6, bufA);
        WAITVM(32);
        COMPUTE(5, bufB);
        ISSUE(7, bufB);
        WAITVM(32);
        COMPUTE(6, bufA);
        WAITVM(8);           // chunk7 done (its 8 atomics... only prior 8 left)
        COMPUTE(7, bufB);
    } else {
        // generic tail (not hit: E % 64 == 0) — plain register gathers
        for (int e = 0; e < nE; ++e) {
            int s_ = __shfl(src, e);
            int d_ = __shfl(dst, e);
            float av = ai[(size_t)s_ * 64 + l];
            float hh = hv[(size_t)d_ * 64 + l];
            float a2 = aj[(size_t)d_ * 64 + l];
            const float4* eav = reinterpret_cast<const float4*>(ea + ((size_t)e0 + e) * 16);
            float4 v0 = eav[0], v1 = eav[1], v2 = eav[2], v3 = eav[3];
            float pre = av + a2;
            FMA16(pre, v0, v1, v2, v3);
            float alpha = pre > 0.f ? pre : 0.2f * pre;
            atomicAdd(&out[(size_t)s_ * 64 + l], hh * alpha);
        }
    }
#undef ISSUE
#undef COMPUTE
#undef FMA16
}

extern "C" void kernel_launch(void* const* d_in, const int* in_sizes, int n_in,
                              void* d_out, int out_size, void* d_ws, size_t ws_size,
                              hipStream_t stream) {
    const float* x     = (const float*)d_in[0];
    const int*   ei    = (const int*)d_in[1];
    const float* ea    = (const float*)d_in[2];
    const float* fc_w  = (const float*)d_in[3];
    const float* fc_b  = (const float*)d_in[4];
    const float* att_w = (const float*)d_in[5];
    const float* att_b = (const float*)d_in[6];
    float* out = (float*)d_out;

    const int N = in_sizes[0] / 128;  // 50000
    const int E = in_sizes[2] / 16;   // 800000

    float* ai = (float*)d_ws;                    // [N*64]
    float* hv = ai + (size_t)N * 64;             // [N*64]
    float* aj = hv + (size_t)N * 64;             // [N*64]

    // out is scatter-accumulated: zero it every call (harness doesn't re-zero)
    hipMemsetAsync(d_out, 0, (size_t)out_size * sizeof(float), stream);

    node_kernel<<<512, 256, 0, stream>>>(x, fc_w, fc_b, att_w, att_b, ai, hv, aj, N);

    const int tiles = (E + 63) / 64;            // one 64-edge tile per wave
    const int eblocks = (tiles + 1) / 2;        // 2 waves per block
    edge_kernel<<<eblocks, 128, 0, stream>>>(ei, ea, ai, hv, aj, att_w, out, E);
}

// Round 6
// 241.698 us; speedup vs baseline: 2.1076x; 2.1076x over previous
//
#include <hip/hip_runtime.h>

// EdgeGATConv: h = x@fc_w^T + fc_b;  alpha = leaky_relu(Wi@h[src] + Wj@h[dst] + We@ea + att_b)
// out[src] += h[dst] * alpha
// N=50000, C=128, H=64, E_DIM=16, E=800000

#define GLDS4(gp, lp)                                                          \
    __builtin_amdgcn_global_load_lds(                                          \
        (const __attribute__((address_space(1))) unsigned int*)(gp),           \
        (__attribute__((address_space(3))) unsigned int*)(lp), 4, 0, 0)
#define GLDS16(gp, lp)                                                         \
    __builtin_amdgcn_global_load_lds(                                          \
        (const __attribute__((address_space(1))) unsigned int*)(gp),           \
        (__attribute__((address_space(3))) unsigned int*)(lp), 16, 0, 0)

#define WAITVM_(n) asm volatile("s_waitcnt vmcnt(" #n ")" ::: "memory")
#define WAITVM(n)                                                              \
    do { WAITVM_(n); __builtin_amdgcn_sched_barrier(0); } while (0)

// Node kernel: EXACT R1 structure (batch-1 per wave, 256 threads). Batching
// weight reuse (R2/R3/R5) always spilled: compiler caps at 128 VGPR for this
// shape and round-trips ~250-500MB through scratch. Batch-1 is the proven
// config (~55us). Only change vs R1: SoA outputs {ai, h, aj} for the DMA
// edge kernel.
__global__ __launch_bounds__(256) void node_kernel(
    const float* __restrict__ x,
    const float* __restrict__ fc_w, const float* __restrict__ fc_b,
    const float* __restrict__ att_w, const float* __restrict__ att_b,
    float* __restrict__ ai_out, float* __restrict__ h_out,
    float* __restrict__ aj_out, int N)
{
    // weights in LDS, chunk-XOR-swizzled for conflict-minimal b128 row reads
    __shared__ __align__(16) float4 wF[64 * 32];  // fc_w rows [64][128]
    __shared__ __align__(16) float4 wI[64 * 16];  // att_w[:, 0:64]
    __shared__ __align__(16) float4 wJ[64 * 16];  // att_w[:, 64:128]
    __shared__ __align__(16) float xs[4][128];
    __shared__ __align__(16) float hs[4][64];

    const int t = threadIdx.x;
    for (int idx = t; idx < 64 * 32; idx += 256) {
        int l = idx >> 5, c = idx & 31;
        wF[l * 32 + (c ^ (l & 31))] =
            *reinterpret_cast<const float4*>(fc_w + l * 128 + c * 4);
    }
    for (int idx = t; idx < 64 * 16; idx += 256) {
        int l = idx >> 4, c = idx & 15;
        wI[l * 16 + (c ^ (l & 15))] =
            *reinterpret_cast<const float4*>(att_w + l * 144 + c * 4);
        wJ[l * 16 + (c ^ (l & 15))] =
            *reinterpret_cast<const float4*>(att_w + l * 144 + 64 + c * 4);
    }
    __syncthreads();

    const int w = t >> 6, l = t & 63;
    const float bF = fc_b[l];
    const float bA = att_b[l];   // fold att_b into a_i
    const int waveId = blockIdx.x * 4 + w;
    const int nWaves = gridDim.x * 4;

    for (int n = waveId; n < N; n += nWaves) {
        float2 xv = reinterpret_cast<const float2*>(x)[(size_t)n * 64 + l];
        xs[w][2 * l] = xv.x;
        xs[w][2 * l + 1] = xv.y;
        float acc = bF;
        #pragma unroll
        for (int c = 0; c < 32; ++c) {
            float4 wv = wF[l * 32 + (c ^ (l & 31))];
            float4 xc = *reinterpret_cast<const float4*>(&xs[w][c * 4]);
            acc = fmaf(wv.x, xc.x, acc);
            acc = fmaf(wv.y, xc.y, acc);
            acc = fmaf(wv.z, xc.z, acc);
            acc = fmaf(wv.w, xc.w, acc);
        }
        hs[w][l] = acc;
        float a2 = bA, a3 = 0.f;
        #pragma unroll
        for (int c = 0; c < 16; ++c) {
            float4 hv = *reinterpret_cast<const float4*>(&hs[w][c * 4]);
            float4 wi = wI[l * 16 + (c ^ (l & 15))];
            float4 wj = wJ[l * 16 + (c ^ (l & 15))];
            a2 = fmaf(wi.x, hv.x, a2); a2 = fmaf(wi.y, hv.y, a2);
            a2 = fmaf(wi.z, hv.z, a2); a2 = fmaf(wi.w, hv.w, a2);
            a3 = fmaf(wj.x, hv.x, a3); a3 = fmaf(wj.y, hv.y, a3);
            a3 = fmaf(wj.z, hv.z, a3); a3 = fmaf(wj.w, hv.w, a3);
        }
        ai_out[(size_t)n * 64 + l] = a2;
        h_out[(size_t)n * 64 + l]  = acc;
        aj_out[(size_t)n * 64 + l] = a3;
    }
}

// Edge kernel (unchanged from R5, proven ~154us): per wave one 64-edge tile.
// Gathers staged via async global_load_lds (wave-uniform base + lane*4),
// 8-edge chunks ping-ponged with COUNTED vmcnt waits (atomics + next chunk
// stay in flight; never drain to 0 in the loop).
__global__ __launch_bounds__(128) void edge_kernel(
    const int* __restrict__ ei,       // [2, E]
    const float* __restrict__ ea,     // [E, 16]
    const float* __restrict__ ai,     // [N, 64]  Wi@h + att_b
    const float* __restrict__ hv,     // [N, 64]  h
    const float* __restrict__ aj,     // [N, 64]  Wj@h
    const float* __restrict__ att_w,  // [64, 144]
    float* __restrict__ out, int E)
{
    // per-wave 16 KiB: ea_s[1024] | bufA[1536] | bufB[1536]
    // buf slot k: ai at +k*192, h at +k*192+64, aj at +k*192+128 (floats)
    __shared__ __align__(16) float lds[2][4096];

    const int t = threadIdx.x, w = t >> 6, l = t & 63;
    float* L = lds[w];
    float* ea_s = L;
    float* bufA = L + 1024;
    float* bufB = L + 2560;

    float we[16];
    #pragma unroll
    for (int k = 0; k < 16; ++k) we[k] = att_w[l * 144 + 128 + k];

    const int waveId = blockIdx.x * 2 + w;
    const int e0 = waveId * 64;
    if (e0 >= E) return;
    const int nE = min(64, E - e0);

    int src = 0, dst = 0;
    if (l < nE) { src = ei[e0 + l]; dst = ei[E + e0 + l]; }

#define ISSUE(c, buf)                                                          \
    {                                                                          \
        _Pragma("unroll") for (int k = 0; k < 8; ++k) {                        \
            int e_ = (c) * 8 + k;                                              \
            int s_ = __shfl(src, e_);                                          \
            int d_ = __shfl(dst, e_);                                          \
            GLDS4(ai + (size_t)s_ * 64 + l, (buf) + k * 192);                  \
            GLDS4(hv + (size_t)d_ * 64 + l, (buf) + k * 192 + 64);             \
            GLDS4(aj + (size_t)d_ * 64 + l, (buf) + k * 192 + 128);            \
        }                                                                      \
    }

#define FMA16(pre, v0, v1, v2, v3)                                             \
    pre = fmaf(we[0], (v0).x, pre);  pre = fmaf(we[1], (v0).y, pre);           \
    pre = fmaf(we[2], (v0).z, pre);  pre = fmaf(we[3], (v0).w, pre);           \
    pre = fmaf(we[4], (v1).x, pre);  pre = fmaf(we[5], (v1).y, pre);           \
    pre = fmaf(we[6], (v1).z, pre);  pre = fmaf(we[7], (v1).w, pre);           \
    pre = fmaf(we[8], (v2).x, pre);  pre = fmaf(we[9], (v2).y, pre);           \
    pre = fmaf(we[10], (v2).z, pre); pre = fmaf(we[11], (v2).w, pre);          \
    pre = fmaf(we[12], (v3).x, pre); pre = fmaf(we[13], (v3).y, pre);          \
    pre = fmaf(we[14], (v3).z, pre); pre = fmaf(we[15], (v3).w, pre)

#define COMPUTE(c, buf)                                                        \
    {                                                                          \
        _Pragma("unroll") for (int k = 0; k < 8; ++k) {                        \
            int e_ = (c) * 8 + k;                                              \
            int s_ = __shfl(src, e_);                                          \
            float av = (buf)[k * 192 + l];                                     \
            float hh = (buf)[k * 192 + 64 + l];                                \
            float a2 = (buf)[k * 192 + 128 + l];                               \
            const float4* eav = reinterpret_cast<const float4*>(ea_s + e_ * 16); \
            float4 v0 = eav[0], v1 = eav[1], v2 = eav[2], v3 = eav[3];         \
            float pre = av + a2;                                               \
            FMA16(pre, v0, v1, v2, v3);                                        \
            float alpha = pre > 0.f ? pre : 0.2f * pre;                        \
            atomicAdd(&out[(size_t)s_ * 64 + l], hh * alpha);                  \
        }                                                                      \
    }

    if (nE == 64) {
        // stage ea tile: 4 x (64 lanes x 16B) = 4 KiB, linear
        #pragma unroll
        for (int r = 0; r < 4; ++r)
            GLDS16(ea + (size_t)e0 * 16 + r * 256 + l * 4, ea_s + r * 256);

        ISSUE(0, bufA);
        ISSUE(1, bufB);
        WAITVM(24);          // ea + chunk0 done (chunk1's 24 still in flight)
        COMPUTE(0, bufA);
        ISSUE(2, bufA);
        WAITVM(32);          // chunk1 done (8 atomics + 24 loads in flight)
        COMPUTE(1, bufB);
        ISSUE(3, bufB);
        WAITVM(32);
        COMPUTE(2, bufA);
        ISSUE(4, bufA);
        WAITVM(32);
        COMPUTE(3, bufB);
        ISSUE(5, bufB);
        WAITVM(32);
        COMPUTE(4, bufA);
        ISSUE(6, bufA);
        WAITVM(32);
        COMPUTE(5, bufB);
        ISSUE(7, bufB);
        WAITVM(32);
        COMPUTE(6, bufA);
        WAITVM(8);           // chunk7 loads done (only its 8 atomics pending)
        COMPUTE(7, bufB);
    } else {
        // generic tail (not hit: E % 64 == 0) — plain register gathers
        for (int e = 0; e < nE; ++e) {
            int s_ = __shfl(src, e);
            int d_ = __shfl(dst, e);
            float av = ai[(size_t)s_ * 64 + l];
            float hh = hv[(size_t)d_ * 64 + l];
            float a2 = aj[(size_t)d_ * 64 + l];
            const float4* eav = reinterpret_cast<const float4*>(ea + ((size_t)e0 + e) * 16);
            float4 v0 = eav[0], v1 = eav[1], v2 = eav[2], v3 = eav[3];
            float pre = av + a2;
            FMA16(pre, v0, v1, v2, v3);
            float alpha = pre > 0.f ? pre : 0.2f * pre;
            atomicAdd(&out[(size_t)s_ * 64 + l], hh * alpha);
        }
    }
#undef ISSUE
#undef COMPUTE
#undef FMA16
}

extern "C" void kernel_launch(void* const* d_in, const int* in_sizes, int n_in,
                              void* d_out, int out_size, void* d_ws, size_t ws_size,
                              hipStream_t stream) {
    const float* x     = (const float*)d_in[0];
    const int*   ei    = (const int*)d_in[1];
    const float* ea    = (const float*)d_in[2];
    const float* fc_w  = (const float*)d_in[3];
    const float* fc_b  = (const float*)d_in[4];
    const float* att_w = (const float*)d_in[5];
    const float* att_b = (const float*)d_in[6];
    float* out = (float*)d_out;

    const int N = in_sizes[0] / 128;  // 50000
    const int E = in_sizes[2] / 16;   // 800000

    float* ai = (float*)d_ws;                    // [N*64]
    float* hv = ai + (size_t)N * 64;             // [N*64]
    float* aj = hv + (size_t)N * 64;             // [N*64]

    // out is scatter-accumulated: zero it every call (harness doesn't re-zero)
    hipMemsetAsync(d_out, 0, (size_t)out_size * sizeof(float), stream);

    node_kernel<<<512, 256, 0, stream>>>(x, fc_w, fc_b, att_w, att_b, ai, hv, aj, N);

    const int tiles = (E + 63) / 64;            // one 64-edge tile per wave
    const int eblocks = (tiles + 1) / 2;        // 2 waves per block
    edge_kernel<<<eblocks, 128, 0, stream>>>(ei, ea, ai, hv, aj, att_w, out, E);
}